// Round 17
// baseline (107.972 us; speedup 1.0000x reference)
//
#include <hip/hip_runtime.h>
#include <cmath>

#define NS 88
#define NL 10
#define NT 30
#define NE 768
#define NH 64
#define NG 256   // 4*H
#define NM 300   // L*T

typedef _Float16 half_t;
typedef __attribute__((ext_vector_type(2))) _Float16 half2_t;
typedef __attribute__((ext_vector_type(8))) _Float16 half8;
typedef __attribute__((ext_vector_type(4))) _Float16 half4v;
typedef __attribute__((ext_vector_type(4))) float f32x4;

__device__ inline void gload_lds16(const void* g, void* l) {
  __builtin_amdgcn_global_load_lds(
      (const __attribute__((address_space(1))) unsigned int*)g,
      (__attribute__((address_space(3))) unsigned int*)l, 16, 0, 0);
}

// fast sigmoid/tanh: v_exp_f32 + v_rcp_f32
__device__ inline float fsigmoid(float x) {
  return __builtin_amdgcn_rcpf(1.f + __expf(-x));
}
__device__ inline float ftanh(float x) {
  float e = __expf(2.f * x);
  return 1.f - 2.f * __builtin_amdgcn_rcpf(e + 1.f);
}

#if __has_builtin(__builtin_amdgcn_fdot2)
__device__ inline float fdot2(half2_t a, half2_t b, float c) {
  return __builtin_amdgcn_fdot2(a, b, c, false);   // v_dot2_f32_f16
}
#else
__device__ inline float fdot2(half2_t a, half2_t b, float c) {
  return fmaf((float)a[1], (float)b[1], fmaf((float)a[0], (float)b[0], c));
}
#endif

__device__ inline half2_t mk_h2(float a, float b) {
  half2_t r; r[0] = (half_t)a; r[1] = (half_t)b; return r;
}

// ---------------------------------------------------------------------------
// convB: Uall_w fp32 [S,768,256] -> fp16 transposed [S,256,768] (n-major,
// k contiguous). LDS 32x32 tile transpose. Grid: S * 24 * 8 blocks.
// ---------------------------------------------------------------------------
__global__ __launch_bounds__(256) void convB_kernel(
    const float* __restrict__ in, half_t* __restrict__ out)
{
  __shared__ float tile[32][36];
  int b  = blockIdx.x;
  int s  = b / 192;
  int r  = b % 192;
  int kt = r / 8;
  int nt = r % 8;
  int t  = threadIdx.x;

  int kk  = t >> 3;
  int nn4 = (t & 7) * 4;
  float4 v = *(const float4*)(in + ((size_t)s * NE + kt * 32 + kk) * NG + nt * 32 + nn4);
  tile[kk][nn4 + 0] = v.x; tile[kk][nn4 + 1] = v.y;
  tile[kk][nn4 + 2] = v.z; tile[kk][nn4 + 3] = v.w;
  __syncthreads();

  int nn = t >> 3;
  int kq = (t & 7) * 4;
  half4v o;
#pragma unroll
  for (int j = 0; j < 4; ++j) o[j] = (half_t)tile[kq + j][nn];
  *(half4v*)(out + ((size_t)s * NG + nt * 32 + nn) * NE + kt * 32 + kq) = o;
}

// ---------------------------------------------------------------------------
// gemm_mfma (R15 exact — stagger reverted): 64m x 256n tile, text read once,
// f16 output. 440 blocks (88 x 5 m-tiles), 4 waves, BK=64, 40KB LDS.
// ---------------------------------------------------------------------------
__global__ __launch_bounds__(256) void gemm_mfma_kernel(
    const float*  __restrict__ text,  // [S,300,768] f32
    const half_t* __restrict__ Bf16,  // [S,256,768] f16 (n-major, k contig)
    const float*  __restrict__ bias,  // [S,256]
    half_t* __restrict__ U)           // [S,300,256] f16
{
  __shared__ uint4 smem4[2560];       // 40 KiB: A 8K @0, B 32K @8192
  char* smem = (char*)smem4;

  int b   = blockIdx.x;
  int swz = (b & 7) * 55 + (b >> 3);  // 440 = 8*55; stock s -> XCD s/11
  int s   = swz / 5;
  int m0  = (swz % 5) * 64;           // 5 m-tiles (rows 300..319 zeroed)

  int tid = threadIdx.x;
  int w = tid >> 6, l = tid & 63;
  int lr = l & 15, lk = l >> 4;       // fragment row, k-group

  const float*  At = text + (size_t)s * NM * NE;
  const half_t* Bb = Bf16 + (size_t)s * NG * NE;

  f32x4 acc[4][4];                    // [m-frag][n-frag]
#pragma unroll
  for (int i = 0; i < 4; ++i)
#pragma unroll
    for (int j = 0; j < 4; ++j) acc[i][j] = (f32x4){0.f, 0.f, 0.f, 0.f};

  for (int step = 0; step < 12; ++step) {
    int k0 = step * 64;
    // stage B: 256 rows x 64k f16 = 32KB (8 gload rounds), inverse-swz src
#pragma unroll
    for (int j = 0; j < 8; ++j) {
      int ci  = j * 256 + tid;
      int row = ci >> 3;
      int c   = (ci & 7) ^ (row & 7);
      gload_lds16(Bb + (size_t)row * NE + k0 + c * 8,
                  smem + 8192 + j * 4096 + w * 1024);
    }
    // stage A: 64 rows x 64k, f32 global -> f16 -> swizzled ds_write_b128
#pragma unroll
    for (int j = 0; j < 2; ++j) {
      int idx = j * 256 + tid;
      int row = idx >> 3, c = idx & 7;
      int m   = m0 + row;
      half8 av;
      if (m < NM) {
        const float* p = At + (size_t)m * NE + k0 + c * 8;
        float4 x = *(const float4*)p;
        float4 y = *(const float4*)(p + 4);
        av[0] = (half_t)x.x; av[1] = (half_t)x.y;
        av[2] = (half_t)x.z; av[3] = (half_t)x.w;
        av[4] = (half_t)y.x; av[5] = (half_t)y.y;
        av[6] = (half_t)y.z; av[7] = (half_t)y.w;
      } else {
#pragma unroll
        for (int q = 0; q < 8; ++q) av[q] = (half_t)0.f;
      }
      *(half8*)(smem + row * 128 + ((c ^ (row & 7)) * 16)) = av;
    }
    __syncthreads();   // drains vmcnt (gload) + lgkmcnt (ds_write)

#pragma unroll
    for (int kk = 0; kk < 2; ++kk) {
      half8 af[4], bf[4];
#pragma unroll
      for (int fm = 0; fm < 4; ++fm) {          // A frags: all 64 m rows
        int rw = fm * 16 + lr;
        int cc = (kk * 4 + lk) ^ (rw & 7);
        af[fm] = *(const half8*)(smem + rw * 128 + cc * 16);
      }
#pragma unroll
      for (int fn = 0; fn < 4; ++fn) {          // B frags: wave's n-quarter
        int rw = w * 64 + fn * 16 + lr;
        int cc = (kk * 4 + lk) ^ (rw & 7);
        bf[fn] = *(const half8*)(smem + 8192 + rw * 128 + cc * 16);
      }
#pragma unroll
      for (int fm = 0; fm < 4; ++fm)
#pragma unroll
        for (int fn = 0; fn < 4; ++fn)
          acc[fm][fn] = __builtin_amdgcn_mfma_f32_16x16x32_f16(
              af[fm], bf[fn], acc[fm][fn], 0, 0, 0);
    }
    __syncthreads();
  }

  // epilogue: D row = lk*4+e, col = lr (m89 layout); add bias, f16 store
#pragma unroll
  for (int fn = 0; fn < 4; ++fn) {
    int col = w * 64 + fn * 16 + lr;
    float bv = bias[(size_t)s * NG + col];
#pragma unroll
    for (int fm = 0; fm < 4; ++fm) {
      int mbase = m0 + fm * 16 + lk * 4;
#pragma unroll
      for (int e = 0; e < 4; ++e) {
        int m = mbase + e;
        if (m < NM)
          U[((size_t)s * NM + m) * NG + col] = (half_t)(acc[fm][fn][e] + bv);
      }
    }
  }
}

// ---------------------------------------------------------------------------
// TimeLSTM + text attention FUSED. One wave per (stock, day), barrier-free.
// NEW: a2[t] (tW2 dot h_t) computed IN-SCAN from the f16 h2_s broadcast
// (same f16 path the gate dots already use) — the post-scan attention phase
// no longer re-reads hist for the 64-FMA dot per t. tw2 held as 32 half2
// (replaces 64 f32 regs).
// ---------------------------------------------------------------------------
__global__ __launch_bounds__(64) void lstm_attn_kernel(
    const half_t* __restrict__ u,      // [S, L*T, 256] f16
    const float* __restrict__ time_in, // [S, L, T]
    const float* __restrict__ Wdw,  const float* __restrict__ Wdb,
    const float* __restrict__ Wallw, const float* __restrict__ Wallb,
    const float* __restrict__ tW1w, const float* __restrict__ tW1b,
    const float* __restrict__ tW2w, const float* __restrict__ tW2b,
    const float* __restrict__ tVw,  const float* __restrict__ tVb,
    float* __restrict__ day_vec)       // [S, L, H]
{
  int b   = blockIdx.x;
  int bid = (b & 7) * 110 + (b >> 3);  // 880 = 8*110; stock s -> XCD s/11
  int s = bid / NL;
  int j = threadIdx.x;                 // 0..63

  __shared__ half_t  u_sh[NT * NG];    // 15 KiB (f16)
  __shared__ float   hist[NT][NH];     // 7.5 KiB
  __shared__ float   ts_s[NT];
  __shared__ half2_t h2_s[NH / 2];
  __shared__ half2_t c2_s[NH / 2];

  // stage u tile: 15 x 1KB (2 rows per gload), per-lane source j*16B
  const half_t* u_base = u + (size_t)bid * NT * NG;
#pragma unroll
  for (int i = 0; i < 15; ++i)
    gload_lds16(u_base + i * 512 + j * 8, (char*)u_sh + i * 1024);

  if (j < NT) ts_s[j] = time_in[(size_t)bid * NT + j];
  ((half_t*)h2_s)[j] = (half_t)0.f;
  ((half_t*)c2_s)[j] = (half_t)0.f;

  // weights -> packed f16 pairs in VGPRs
  const float* Wa  = Wallw + (size_t)s * NH * NG;
  const float* Wdp = Wdw   + (size_t)s * NH * NH;
  const float* tW2p = tW2w + (size_t)s * NH * NH;
  half2_t wf[32], wi[32], wo[32], wg[32], wd[32], tw2h[32];
#pragma unroll
  for (int k2 = 0; k2 < 32; ++k2) {
    wf[k2]   = mk_h2(Wa[(2*k2) * NG + j],        Wa[(2*k2+1) * NG + j]);
    wi[k2]   = mk_h2(Wa[(2*k2) * NG + 64 + j],   Wa[(2*k2+1) * NG + 64 + j]);
    wo[k2]   = mk_h2(Wa[(2*k2) * NG + 128 + j],  Wa[(2*k2+1) * NG + 128 + j]);
    wg[k2]   = mk_h2(Wa[(2*k2) * NG + 192 + j],  Wa[(2*k2+1) * NG + 192 + j]);
    wd[k2]   = mk_h2(Wdp[(2*k2) * NH + j],       Wdp[(2*k2+1) * NH + j]);
    tw2h[k2] = mk_h2(tW2p[(2*k2) * NH + j],      tW2p[(2*k2+1) * NH + j]);
  }
  float bf = Wallb[(size_t)s * NG + j];
  float bi = Wallb[(size_t)s * NG + 64 + j];
  float bo = Wallb[(size_t)s * NG + 128 + j];
  float bg = Wallb[(size_t)s * NG + 192 + j];
  float bd = Wdb[(size_t)s * NH + j];
  float b2k = tW2b[(size_t)s * NH + j];

  // drain global_load_lds before reading u_sh (single wave: no barrier)
  asm volatile("s_waitcnt vmcnt(0)" ::: "memory");

  float sc[NT];                        // in-scan a2[t], then scores
  float c_my = 0.f;
  for (int t = 0; t < NT; ++t) {
    float accf = bf + (float)u_sh[t * NG + j];
    float acci = bi + (float)u_sh[t * NG + 64 + j];
    float acco = bo + (float)u_sh[t * NG + 128 + j];
    float accg = bg + (float)u_sh[t * NG + 192 + j];
    float accd = bd;
#pragma unroll
    for (int k2 = 0; k2 < 32; ++k2) {
      half2_t hv = h2_s[k2];
      half2_t cv = c2_s[k2];
      accf = fdot2(hv, wf[k2], accf);
      acci = fdot2(hv, wi[k2], acci);
      acco = fdot2(hv, wo[k2], acco);
      accg = fdot2(hv, wg[k2], accg);
      accd = fdot2(cv, wd[k2], accd);
    }
    float f  = fsigmoid(accf);          // reference: all-sigmoid gates
    float ii = fsigmoid(acci);
    float o  = fsigmoid(acco);
    float gg = fsigmoid(accg);
    float cadj = c_my + ftanh(accd) * (ts_s[t] - 1.f);
    float cn = fmaf(f, cadj, ii * gg);
    c_my = cn;
    float hn = o * ftanh(cn);
    ((half_t*)h2_s)[j] = (half_t)hn;
    ((half_t*)c2_s)[j] = (half_t)cn;
    hist[t][j] = hn;                    // keep history in LDS (f32)

    // in-scan a2[t][j] = tW2 col j . h_t  (reads the just-updated h2_s;
    // same-wave ds ordering guarantees visibility)
    float a2 = b2k;
#pragma unroll
    for (int k2 = 0; k2 < 32; ++k2)
      a2 = fdot2(h2_s[k2], tw2h[k2], a2);
    sc[t] = a2;
  }

  // ---- text attention over T (a2 precomputed; only a1 + score left) ----
  const float* tW1p = tW1w + (size_t)s * NH * NH;

  float a1 = tW1b[(size_t)s * NH + j];
  {
    const float4* h4 = (const float4*)&hist[NT - 1][0];
#pragma unroll
    for (int q = 0; q < NH / 4; ++q) {
      float4 v = h4[q];
      a1 = fmaf(v.x, tW1p[(size_t)(4*q+0) * NH + j], a1);
      a1 = fmaf(v.y, tW1p[(size_t)(4*q+1) * NH + j], a1);
      a1 = fmaf(v.z, tW1p[(size_t)(4*q+2) * NH + j], a1);
      a1 = fmaf(v.w, tW1p[(size_t)(4*q+3) * NH + j], a1);
    }
  }
  float tv  = tVw[(size_t)s * NH + j];
  float tvb = tVb[s];

#pragma unroll
  for (int t = 0; t < NT; ++t) {
    float v = ftanh(a1 + sc[t]) * tv;
#pragma unroll
    for (int off = 32; off >= 1; off >>= 1) v += __shfl_xor(v, off);
    sc[t] = v + tvb;
  }
  float mx = sc[0];
#pragma unroll
  for (int t = 1; t < NT; ++t) mx = fmaxf(mx, sc[t]);
  float sum = 0.f;
#pragma unroll
  for (int t = 0; t < NT; ++t) { sc[t] = __expf(sc[t] - mx); sum += sc[t]; }
  float inv = __builtin_amdgcn_rcpf(sum);
  float dv = 0.f;
#pragma unroll
  for (int t = 0; t < NT; ++t) dv = fmaf(sc[t] * inv, hist[t][j], dv);
  day_vec[(size_t)bid * NH + j] = dv;
}

// ---------------------------------------------------------------------------
// day LSTM + day attention + pred head. One block per stock, XCD-aligned.
// ---------------------------------------------------------------------------
__global__ __launch_bounds__(256) void day_head_kernel(
    const float* __restrict__ day_vec, // [S, L, H]
    const float* __restrict__ ihw, const float* __restrict__ ihb,
    const float* __restrict__ hhb,
    const float* __restrict__ dW1w, const float* __restrict__ dW1b,
    const float* __restrict__ dW2w, const float* __restrict__ dW2b,
    const float* __restrict__ dVw,  const float* __restrict__ dVb,
    const float* __restrict__ predw, const float* __restrict__ predb,
    float* __restrict__ out)           // [S]
{
  int b = blockIdx.x;
  int s = (b & 7) * 11 + (b >> 3);     // 88 = 8*11; stock s -> XCD s/11
  int g = threadIdx.x;
  int j = g & 63;
  int q = g >> 6;

  __shared__ float dv_s[NL][NH];
  __shared__ float gl[NL][NG];
  __shared__ float hd[NL][NH];

  for (int i = g; i < NL * NH; i += 256)
    ((float*)dv_s)[i] = day_vec[(size_t)s * NL * NH + i];
  __syncthreads();

  float ihcol[NH];
#pragma unroll
  for (int k = 0; k < NH; ++k)
    ihcol[k] = ihw[((size_t)s * NH + k) * NG + g];
  float bias = ihb[(size_t)s * NG + g] + hhb[(size_t)s * NG + g];

  bool is_gpart = (g >= 128 && g < 192);
  for (int l = 0; l < NL; ++l) {
    float acc = bias;
#pragma unroll
    for (int k = 0; k < NH; ++k) acc = fmaf(dv_s[l][k], ihcol[k], acc);
    gl[l][g] = is_gpart ? ftanh(acc) : fsigmoid(acc);
  }
  __syncthreads();
  for (int l = q; l < NL; l += 4) {
    float cd = gl[l][j] * gl[l][128 + j];       // sig(i)*tanh(g)
    hd[l][j] = gl[l][192 + j] * ftanh(cd);      // sig(o)*tanh(c)
  }
  __syncthreads();

  if (g < 64) {
    int k = g;
    float dw1c[NH], dw2c[NH];
#pragma unroll
    for (int h = 0; h < NH; ++h) {
      dw1c[h] = dW1w[((size_t)s * NH + h) * NH + k];
      dw2c[h] = dW2w[((size_t)s * NH + h) * NH + k];
    }
    float b1 = dW1b[(size_t)s * NH + k];
    float b2 = dW2b[(size_t)s * NH + k];
    float dv = dVw[(size_t)s * NH + k];
    float dvb = dVb[s];

    float sc[NL];
#pragma unroll
    for (int l = 0; l < NL; ++l) {
      float x1 = b1, x2 = b2;
#pragma unroll
      for (int h = 0; h < NH; ++h) {
        x1 = fmaf(hd[l][h], dw1c[h], x1);
        x2 = fmaf(hd[l][h], dw2c[h], x2);
      }
      float v = ftanh(x1 + x2) * dv;
#pragma unroll
      for (int off = 32; off >= 1; off >>= 1) v += __shfl_xor(v, off);
      sc[l] = v + dvb;
    }
    float mx = sc[0];
#pragma unroll
    for (int l = 1; l < NL; ++l) mx = fmaxf(mx, sc[l]);
    float sum = 0.f;
#pragma unroll
    for (int l = 0; l < NL; ++l) { sc[l] = __expf(sc[l] - mx); sum += sc[l]; }
    float inv = __builtin_amdgcn_rcpf(sum);
    float sv = 0.f;
#pragma unroll
    for (int l = 0; l < NL; ++l) sv = fmaf(sc[l] * inv, hd[l][k], sv);

    float p = sv * predw[k];
#pragma unroll
    for (int off = 32; off >= 1; off >>= 1) p += __shfl_xor(p, off);
    if (k == 0) {
      float x = p + predb[0];
      out[s] = (x >= 0.f) ? x : 0.01f * x;
    }
  }
}

// ---------------------------------------------------------------------------
extern "C" void kernel_launch(void* const* d_in, const int* in_sizes, int n_in,
                              void* d_out, int out_size, void* d_ws, size_t ws_size,
                              hipStream_t stream) {
  (void)in_sizes; (void)n_in; (void)out_size; (void)ws_size;

  const float* text    = (const float*)d_in[0];
  const float* time_in = (const float*)d_in[1];
  const float* Wdw     = (const float*)d_in[2];
  const float* Wdb     = (const float*)d_in[3];
  const float* Wallw   = (const float*)d_in[4];
  const float* Wallb   = (const float*)d_in[5];
  const float* Uallw   = (const float*)d_in[6];
  const float* Uallb   = (const float*)d_in[7];
  const float* tW1w    = (const float*)d_in[8];
  const float* tW1b    = (const float*)d_in[9];
  const float* tW2w    = (const float*)d_in[10];
  const float* tW2b    = (const float*)d_in[11];
  const float* tVw     = (const float*)d_in[12];
  const float* tVb     = (const float*)d_in[13];
  const float* ihw     = (const float*)d_in[14];
  const float* ihb     = (const float*)d_in[15];
  const float* hhb     = (const float*)d_in[16];
  const float* dW1w    = (const float*)d_in[17];
  const float* dW1b    = (const float*)d_in[18];
  const float* dW2w    = (const float*)d_in[19];
  const float* dW2b    = (const float*)d_in[20];
  const float* dVw     = (const float*)d_in[21];
  const float* dVb     = (const float*)d_in[22];
  const float* predw   = (const float*)d_in[23];
  const float* predb   = (const float*)d_in[24];

  float* ws      = (float*)d_ws;
  float* day_vec = ws;                                       // S*L*H f32
  half_t* Bf16   = (half_t*)(day_vec + (size_t)NS * NL * NH);// S*256*768 f16
  half_t* u      = Bf16 + (size_t)NS * NG * NE;              // S*300*256 f16

  convB_kernel<<<NS * 192, 256, 0, stream>>>(Uallw, Bf16);
  gemm_mfma_kernel<<<NS * 5, 256, 0, stream>>>(text, Bf16, Uallb, u);
  lstm_attn_kernel<<<NS * NL, 64, 0, stream>>>(u, time_in, Wdw, Wdb,
                                               Wallw, Wallb,
                                               tW1w, tW1b, tW2w, tW2b,
                                               tVw, tVb, day_vec);
  day_head_kernel<<<NS, 256, 0, stream>>>(day_vec, ihw, ihb, hhb,
                                          dW1w, dW1b, dW2w, dW2b, dVw, dVb,
                                          predw, predb, (float*)d_out);
}

// Round 18
// 102.341 us; speedup vs baseline: 1.0550x; 1.0550x over previous
//
#include <hip/hip_runtime.h>
#include <cmath>

#define NS 88
#define NL 10
#define NT 30
#define NE 768
#define NH 64
#define NG 256   // 4*H
#define NM 300   // L*T

typedef _Float16 half_t;
typedef __attribute__((ext_vector_type(2))) _Float16 half2_t;
typedef __attribute__((ext_vector_type(8))) _Float16 half8;
typedef __attribute__((ext_vector_type(4))) _Float16 half4v;
typedef __attribute__((ext_vector_type(4))) float f32x4;

__device__ inline void gload_lds16(const void* g, void* l) {
  __builtin_amdgcn_global_load_lds(
      (const __attribute__((address_space(1))) unsigned int*)g,
      (__attribute__((address_space(3))) unsigned int*)l, 16, 0, 0);
}

// fast sigmoid/tanh: v_exp_f32 + v_rcp_f32
__device__ inline float fsigmoid(float x) {
  return __builtin_amdgcn_rcpf(1.f + __expf(-x));
}
__device__ inline float ftanh(float x) {
  float e = __expf(2.f * x);
  return 1.f - 2.f * __builtin_amdgcn_rcpf(e + 1.f);
}

#if __has_builtin(__builtin_amdgcn_fdot2)
__device__ inline float fdot2(half2_t a, half2_t b, float c) {
  return __builtin_amdgcn_fdot2(a, b, c, false);   // v_dot2_f32_f16
}
#else
__device__ inline float fdot2(half2_t a, half2_t b, float c) {
  return fmaf((float)a[1], (float)b[1], fmaf((float)a[0], (float)b[0], c));
}
#endif

__device__ inline half2_t mk_h2(float a, float b) {
  half2_t r; r[0] = (half_t)a; r[1] = (half_t)b; return r;
}

// ---------------------------------------------------------------------------
// convB: Uall_w fp32 [S,768,256] -> fp16 transposed [S,256,768] (n-major,
// k contiguous). LDS 32x32 tile transpose. Grid: S * 24 * 8 blocks.
// ---------------------------------------------------------------------------
__global__ __launch_bounds__(256) void convB_kernel(
    const float* __restrict__ in, half_t* __restrict__ out)
{
  __shared__ float tile[32][36];
  int b  = blockIdx.x;
  int s  = b / 192;
  int r  = b % 192;
  int kt = r / 8;
  int nt = r % 8;
  int t  = threadIdx.x;

  int kk  = t >> 3;
  int nn4 = (t & 7) * 4;
  float4 v = *(const float4*)(in + ((size_t)s * NE + kt * 32 + kk) * NG + nt * 32 + nn4);
  tile[kk][nn4 + 0] = v.x; tile[kk][nn4 + 1] = v.y;
  tile[kk][nn4 + 2] = v.z; tile[kk][nn4 + 3] = v.w;
  __syncthreads();

  int nn = t >> 3;
  int kq = (t & 7) * 4;
  half4v o;
#pragma unroll
  for (int j = 0; j < 4; ++j) o[j] = (half_t)tile[kq + j][nn];
  *(half4v*)(out + ((size_t)s * NG + nt * 32 + nn) * NE + kt * 32 + kq) = o;
}

// ---------------------------------------------------------------------------
// gemm_mfma (R15 exact): 64m x 256n tile, text read once, f16 output.
// 440 blocks (88 x 5 m-tiles), 4 waves, BK=64, 40KB LDS -> 4 blocks/CU.
// ---------------------------------------------------------------------------
__global__ __launch_bounds__(256) void gemm_mfma_kernel(
    const float*  __restrict__ text,  // [S,300,768] f32
    const half_t* __restrict__ Bf16,  // [S,256,768] f16 (n-major, k contig)
    const float*  __restrict__ bias,  // [S,256]
    half_t* __restrict__ U)           // [S,300,256] f16
{
  __shared__ uint4 smem4[2560];       // 40 KiB: A 8K @0, B 32K @8192
  char* smem = (char*)smem4;

  int b   = blockIdx.x;
  int swz = (b & 7) * 55 + (b >> 3);  // 440 = 8*55; stock s -> XCD s/11
  int s   = swz / 5;
  int m0  = (swz % 5) * 64;           // 5 m-tiles (rows 300..319 zeroed)

  int tid = threadIdx.x;
  int w = tid >> 6, l = tid & 63;
  int lr = l & 15, lk = l >> 4;       // fragment row, k-group

  const float*  At = text + (size_t)s * NM * NE;
  const half_t* Bb = Bf16 + (size_t)s * NG * NE;

  f32x4 acc[4][4];                    // [m-frag][n-frag]
#pragma unroll
  for (int i = 0; i < 4; ++i)
#pragma unroll
    for (int j = 0; j < 4; ++j) acc[i][j] = (f32x4){0.f, 0.f, 0.f, 0.f};

  for (int step = 0; step < 12; ++step) {
    int k0 = step * 64;
    // stage B: 256 rows x 64k f16 = 32KB (8 gload rounds), inverse-swz src
#pragma unroll
    for (int j = 0; j < 8; ++j) {
      int ci  = j * 256 + tid;
      int row = ci >> 3;
      int c   = (ci & 7) ^ (row & 7);
      gload_lds16(Bb + (size_t)row * NE + k0 + c * 8,
                  smem + 8192 + j * 4096 + w * 1024);
    }
    // stage A: 64 rows x 64k, f32 global -> f16 -> swizzled ds_write_b128
#pragma unroll
    for (int j = 0; j < 2; ++j) {
      int idx = j * 256 + tid;
      int row = idx >> 3, c = idx & 7;
      int m   = m0 + row;
      half8 av;
      if (m < NM) {
        const float* p = At + (size_t)m * NE + k0 + c * 8;
        float4 x = *(const float4*)p;
        float4 y = *(const float4*)(p + 4);
        av[0] = (half_t)x.x; av[1] = (half_t)x.y;
        av[2] = (half_t)x.z; av[3] = (half_t)x.w;
        av[4] = (half_t)y.x; av[5] = (half_t)y.y;
        av[6] = (half_t)y.z; av[7] = (half_t)y.w;
      } else {
#pragma unroll
        for (int q = 0; q < 8; ++q) av[q] = (half_t)0.f;
      }
      *(half8*)(smem + row * 128 + ((c ^ (row & 7)) * 16)) = av;
    }
    __syncthreads();   // drains vmcnt (gload) + lgkmcnt (ds_write)

#pragma unroll
    for (int kk = 0; kk < 2; ++kk) {
      half8 af[4], bf[4];
#pragma unroll
      for (int fm = 0; fm < 4; ++fm) {          // A frags: all 64 m rows
        int rw = fm * 16 + lr;
        int cc = (kk * 4 + lk) ^ (rw & 7);
        af[fm] = *(const half8*)(smem + rw * 128 + cc * 16);
      }
#pragma unroll
      for (int fn = 0; fn < 4; ++fn) {          // B frags: wave's n-quarter
        int rw = w * 64 + fn * 16 + lr;
        int cc = (kk * 4 + lk) ^ (rw & 7);
        bf[fn] = *(const half8*)(smem + 8192 + rw * 128 + cc * 16);
      }
#pragma unroll
      for (int fm = 0; fm < 4; ++fm)
#pragma unroll
        for (int fn = 0; fn < 4; ++fn)
          acc[fm][fn] = __builtin_amdgcn_mfma_f32_16x16x32_f16(
              af[fm], bf[fn], acc[fm][fn], 0, 0, 0);
    }
    __syncthreads();
  }

  // epilogue: D row = lk*4+e, col = lr (m89 layout); add bias, f16 store
#pragma unroll
  for (int fn = 0; fn < 4; ++fn) {
    int col = w * 64 + fn * 16 + lr;
    float bv = bias[(size_t)s * NG + col];
#pragma unroll
    for (int fm = 0; fm < 4; ++fm) {
      int mbase = m0 + fm * 16 + lk * 4;
#pragma unroll
      for (int e = 0; e < 4; ++e) {
        int m = mbase + e;
        if (m < NM)
          U[((size_t)s * NM + m) * NG + col] = (half_t)(acc[fm][fn][e] + bv);
      }
    }
  }
}

// ---------------------------------------------------------------------------
// TimeLSTM + text attention FUSED (R15 exact). One wave per (stock, day),
// barrier-free. u f16 (15KB stage). XCD swizzle aligned with gemm.
// a2 computed POST-SCAN from hist (parallel/pipelined phase — the R17
// in-scan variant lengthened the serial critical path and regressed).
// ---------------------------------------------------------------------------
__global__ __launch_bounds__(64) void lstm_attn_kernel(
    const half_t* __restrict__ u,      // [S, L*T, 256] f16
    const float* __restrict__ time_in, // [S, L, T]
    const float* __restrict__ Wdw,  const float* __restrict__ Wdb,
    const float* __restrict__ Wallw, const float* __restrict__ Wallb,
    const float* __restrict__ tW1w, const float* __restrict__ tW1b,
    const float* __restrict__ tW2w, const float* __restrict__ tW2b,
    const float* __restrict__ tVw,  const float* __restrict__ tVb,
    float* __restrict__ day_vec)       // [S, L, H]
{
  int b   = blockIdx.x;
  int bid = (b & 7) * 110 + (b >> 3);  // 880 = 8*110; stock s -> XCD s/11
  int s = bid / NL;
  int j = threadIdx.x;                 // 0..63

  __shared__ half_t  u_sh[NT * NG];    // 15 KiB (f16)
  __shared__ float   hist[NT][NH];     // 7.5 KiB
  __shared__ float   ts_s[NT];
  __shared__ half2_t h2_s[NH / 2];
  __shared__ half2_t c2_s[NH / 2];

  // stage u tile: 15 x 1KB (2 rows per gload), per-lane source j*16B
  const half_t* u_base = u + (size_t)bid * NT * NG;
#pragma unroll
  for (int i = 0; i < 15; ++i)
    gload_lds16(u_base + i * 512 + j * 8, (char*)u_sh + i * 1024);

  if (j < NT) ts_s[j] = time_in[(size_t)bid * NT + j];
  ((half_t*)h2_s)[j] = (half_t)0.f;
  ((half_t*)c2_s)[j] = (half_t)0.f;

  // weights -> packed f16 pairs in VGPRs
  const float* Wa  = Wallw + (size_t)s * NH * NG;
  const float* Wdp = Wdw   + (size_t)s * NH * NH;
  half2_t wf[32], wi[32], wo[32], wg[32], wd[32];
#pragma unroll
  for (int k2 = 0; k2 < 32; ++k2) {
    wf[k2] = mk_h2(Wa[(2*k2) * NG + j],        Wa[(2*k2+1) * NG + j]);
    wi[k2] = mk_h2(Wa[(2*k2) * NG + 64 + j],   Wa[(2*k2+1) * NG + 64 + j]);
    wo[k2] = mk_h2(Wa[(2*k2) * NG + 128 + j],  Wa[(2*k2+1) * NG + 128 + j]);
    wg[k2] = mk_h2(Wa[(2*k2) * NG + 192 + j],  Wa[(2*k2+1) * NG + 192 + j]);
    wd[k2] = mk_h2(Wdp[(2*k2) * NH + j],       Wdp[(2*k2+1) * NH + j]);
  }
  float bf = Wallb[(size_t)s * NG + j];
  float bi = Wallb[(size_t)s * NG + 64 + j];
  float bo = Wallb[(size_t)s * NG + 128 + j];
  float bg = Wallb[(size_t)s * NG + 192 + j];
  float bd = Wdb[(size_t)s * NH + j];

  // drain global_load_lds before reading u_sh (single wave: no barrier)
  asm volatile("s_waitcnt vmcnt(0)" ::: "memory");

  float c_my = 0.f;
  for (int t = 0; t < NT; ++t) {
    float accf = bf + (float)u_sh[t * NG + j];
    float acci = bi + (float)u_sh[t * NG + 64 + j];
    float acco = bo + (float)u_sh[t * NG + 128 + j];
    float accg = bg + (float)u_sh[t * NG + 192 + j];
    float accd = bd;
#pragma unroll
    for (int k2 = 0; k2 < 32; ++k2) {
      half2_t hv = h2_s[k2];
      half2_t cv = c2_s[k2];
      accf = fdot2(hv, wf[k2], accf);
      acci = fdot2(hv, wi[k2], acci);
      acco = fdot2(hv, wo[k2], acco);
      accg = fdot2(hv, wg[k2], accg);
      accd = fdot2(cv, wd[k2], accd);
    }
    float f  = fsigmoid(accf);          // reference: all-sigmoid gates
    float ii = fsigmoid(acci);
    float o  = fsigmoid(acco);
    float gg = fsigmoid(accg);
    float cadj = c_my + ftanh(accd) * (ts_s[t] - 1.f);
    float cn = fmaf(f, cadj, ii * gg);
    c_my = cn;
    float hn = o * ftanh(cn);
    ((half_t*)h2_s)[j] = (half_t)hn;
    ((half_t*)c2_s)[j] = (half_t)cn;
    hist[t][j] = hn;                    // keep history in LDS (f32)
  }

  // ---- text attention over T (same wave; hist complete, ds-ordered) ----
  const float* tW1p = tW1w + (size_t)s * NH * NH;
  const float* tW2p = tW2w + (size_t)s * NH * NH;

  float tw2c[NH];                       // tW2 column j in regs
#pragma unroll
  for (int h = 0; h < NH; ++h) tw2c[h] = tW2p[(size_t)h * NH + j];

  float a1 = tW1b[(size_t)s * NH + j];
  {
    const float4* h4 = (const float4*)&hist[NT - 1][0];
#pragma unroll
    for (int q = 0; q < NH / 4; ++q) {
      float4 v = h4[q];
      a1 = fmaf(v.x, tW1p[(size_t)(4*q+0) * NH + j], a1);
      a1 = fmaf(v.y, tW1p[(size_t)(4*q+1) * NH + j], a1);
      a1 = fmaf(v.z, tW1p[(size_t)(4*q+2) * NH + j], a1);
      a1 = fmaf(v.w, tW1p[(size_t)(4*q+3) * NH + j], a1);
    }
  }
  float b2k = tW2b[(size_t)s * NH + j];
  float tv  = tVw[(size_t)s * NH + j];
  float tvb = tVb[s];

  float sc[NT];
#pragma unroll
  for (int t = 0; t < NT; ++t) {
    float a2 = b2k;
    const float4* h4 = (const float4*)&hist[t][0];
#pragma unroll
    for (int q = 0; q < NH / 4; ++q) {
      float4 v = h4[q];
      a2 = fmaf(v.x, tw2c[4*q+0], a2);
      a2 = fmaf(v.y, tw2c[4*q+1], a2);
      a2 = fmaf(v.z, tw2c[4*q+2], a2);
      a2 = fmaf(v.w, tw2c[4*q+3], a2);
    }
    float v = ftanh(a1 + a2) * tv;
#pragma unroll
    for (int off = 32; off >= 1; off >>= 1) v += __shfl_xor(v, off);
    sc[t] = v + tvb;
  }
  float mx = sc[0];
#pragma unroll
  for (int t = 1; t < NT; ++t) mx = fmaxf(mx, sc[t]);
  float sum = 0.f;
#pragma unroll
  for (int t = 0; t < NT; ++t) { sc[t] = __expf(sc[t] - mx); sum += sc[t]; }
  float inv = __builtin_amdgcn_rcpf(sum);
  float dv = 0.f;
#pragma unroll
  for (int t = 0; t < NT; ++t) dv = fmaf(sc[t] * inv, hist[t][j], dv);
  day_vec[(size_t)bid * NH + j] = dv;
}

// ---------------------------------------------------------------------------
// day LSTM + day attention + pred head. One block per stock, XCD-aligned.
// ---------------------------------------------------------------------------
__global__ __launch_bounds__(256) void day_head_kernel(
    const float* __restrict__ day_vec, // [S, L, H]
    const float* __restrict__ ihw, const float* __restrict__ ihb,
    const float* __restrict__ hhb,
    const float* __restrict__ dW1w, const float* __restrict__ dW1b,
    const float* __restrict__ dW2w, const float* __restrict__ dW2b,
    const float* __restrict__ dVw,  const float* __restrict__ dVb,
    const float* __restrict__ predw, const float* __restrict__ predb,
    float* __restrict__ out)           // [S]
{
  int b = blockIdx.x;
  int s = (b & 7) * 11 + (b >> 3);     // 88 = 8*11; stock s -> XCD s/11
  int g = threadIdx.x;
  int j = g & 63;
  int q = g >> 6;

  __shared__ float dv_s[NL][NH];
  __shared__ float gl[NL][NG];
  __shared__ float hd[NL][NH];

  for (int i = g; i < NL * NH; i += 256)
    ((float*)dv_s)[i] = day_vec[(size_t)s * NL * NH + i];
  __syncthreads();

  float ihcol[NH];
#pragma unroll
  for (int k = 0; k < NH; ++k)
    ihcol[k] = ihw[((size_t)s * NH + k) * NG + g];
  float bias = ihb[(size_t)s * NG + g] + hhb[(size_t)s * NG + g];

  bool is_gpart = (g >= 128 && g < 192);
  for (int l = 0; l < NL; ++l) {
    float acc = bias;
#pragma unroll
    for (int k = 0; k < NH; ++k) acc = fmaf(dv_s[l][k], ihcol[k], acc);
    gl[l][g] = is_gpart ? ftanh(acc) : fsigmoid(acc);
  }
  __syncthreads();
  for (int l = q; l < NL; l += 4) {
    float cd = gl[l][j] * gl[l][128 + j];       // sig(i)*tanh(g)
    hd[l][j] = gl[l][192 + j] * ftanh(cd);      // sig(o)*tanh(c)
  }
  __syncthreads();

  if (g < 64) {
    int k = g;
    float dw1c[NH], dw2c[NH];
#pragma unroll
    for (int h = 0; h < NH; ++h) {
      dw1c[h] = dW1w[((size_t)s * NH + h) * NH + k];
      dw2c[h] = dW2w[((size_t)s * NH + h) * NH + k];
    }
    float b1 = dW1b[(size_t)s * NH + k];
    float b2 = dW2b[(size_t)s * NH + k];
    float dv = dVw[(size_t)s * NH + k];
    float dvb = dVb[s];

    float sc[NL];
#pragma unroll
    for (int l = 0; l < NL; ++l) {
      float x1 = b1, x2 = b2;
#pragma unroll
      for (int h = 0; h < NH; ++h) {
        x1 = fmaf(hd[l][h], dw1c[h], x1);
        x2 = fmaf(hd[l][h], dw2c[h], x2);
      }
      float v = ftanh(x1 + x2) * dv;
#pragma unroll
      for (int off = 32; off >= 1; off >>= 1) v += __shfl_xor(v, off);
      sc[l] = v + dvb;
    }
    float mx = sc[0];
#pragma unroll
    for (int l = 1; l < NL; ++l) mx = fmaxf(mx, sc[l]);
    float sum = 0.f;
#pragma unroll
    for (int l = 0; l < NL; ++l) { sc[l] = __expf(sc[l] - mx); sum += sc[l]; }
    float inv = __builtin_amdgcn_rcpf(sum);
    float sv = 0.f;
#pragma unroll
    for (int l = 0; l < NL; ++l) sv = fmaf(sc[l] * inv, hd[l][k], sv);

    float p = sv * predw[k];
#pragma unroll
    for (int off = 32; off >= 1; off >>= 1) p += __shfl_xor(p, off);
    if (k == 0) {
      float x = p + predb[0];
      out[s] = (x >= 0.f) ? x : 0.01f * x;
    }
  }
}

// ---------------------------------------------------------------------------
extern "C" void kernel_launch(void* const* d_in, const int* in_sizes, int n_in,
                              void* d_out, int out_size, void* d_ws, size_t ws_size,
                              hipStream_t stream) {
  (void)in_sizes; (void)n_in; (void)out_size; (void)ws_size;

  const float* text    = (const float*)d_in[0];
  const float* time_in = (const float*)d_in[1];
  const float* Wdw     = (const float*)d_in[2];
  const float* Wdb     = (const float*)d_in[3];
  const float* Wallw   = (const float*)d_in[4];
  const float* Wallb   = (const float*)d_in[5];
  const float* Uallw   = (const float*)d_in[6];
  const float* Uallb   = (const float*)d_in[7];
  const float* tW1w    = (const float*)d_in[8];
  const float* tW1b    = (const float*)d_in[9];
  const float* tW2w    = (const float*)d_in[10];
  const float* tW2b    = (const float*)d_in[11];
  const float* tVw     = (const float*)d_in[12];
  const float* tVb     = (const float*)d_in[13];
  const float* ihw     = (const float*)d_in[14];
  const float* ihb     = (const float*)d_in[15];
  const float* hhb     = (const float*)d_in[16];
  const float* dW1w    = (const float*)d_in[17];
  const float* dW1b    = (const float*)d_in[18];
  const float* dW2w    = (const float*)d_in[19];
  const float* dW2b    = (const float*)d_in[20];
  const float* dVw     = (const float*)d_in[21];
  const float* dVb     = (const float*)d_in[22];
  const float* predw   = (const float*)d_in[23];
  const float* predb   = (const float*)d_in[24];

  float* ws      = (float*)d_ws;
  float* day_vec = ws;                                       // S*L*H f32
  half_t* Bf16   = (half_t*)(day_vec + (size_t)NS * NL * NH);// S*256*768 f16
  half_t* u      = Bf16 + (size_t)NS * NG * NE;              // S*300*256 f16

  convB_kernel<<<NS * 192, 256, 0, stream>>>(Uallw, Bf16);
  gemm_mfma_kernel<<<NS * 5, 256, 0, stream>>>(text, Bf16, Uallb, u);
  lstm_attn_kernel<<<NS * NL, 64, 0, stream>>>(u, time_in, Wdw, Wdb,
                                               Wallw, Wallb,
                                               tW1w, tW1b, tW2w, tW2b,
                                               tVw, tVb, day_vec);
  day_head_kernel<<<NS, 256, 0, stream>>>(day_vec, ihw, ihb, hhb,
                                          dW1w, dW1b, dW2w, dW2b, dVw, dVb,
                                          predw, predb, (float*)d_out);
}